// Round 4
// baseline (74.418 us; speedup 1.0000x reference)
//
#include <hip/hip_runtime.h>
#include <math.h>

#define BB 16
#define NN 2048
#define CCH 81
#define GG 16
#define NCLS 80
#define CAP 256   // per-(image,class) candidate cap; mean ~26, 256 = >40 sigma

typedef unsigned long long u64;
typedef unsigned int u32;

__device__ __forceinline__ float iou4(float4 a, float4 b) {
    float areaA = (a.z - a.x) * (a.w - a.y);
    float areaB = (b.z - b.x) * (b.w - b.y);
    float ltx = fmaxf(a.x, b.x), lty = fmaxf(a.y, b.y);
    float rbx = fminf(a.z, b.z), rby = fminf(a.w, b.w);
    float w = fmaxf(rbx - ltx, 0.0f), h = fmaxf(rby - lty, 0.0f);
    float inter = w * h;
    return inter / (areaA + areaB - inter + 1e-9f);
}

// ctrl layout (u32): [0,1280) ccnt  [1280,1296) hcnt  [1296,1312) ocnt  [1312] done
#define CTRL_WORDS 1313

// Kernel 1: 8 threads/box. Online softmax + argmax + gt-IoU + CE; active boxes
// append their priority key (score | ~idx) to the per-(image,class) list.
__global__ void __launch_bounds__(256) k_perbox(const float* __restrict__ boxes,
                                                const float* __restrict__ logits,
                                                const float* __restrict__ gtb,
                                                const int* __restrict__ gtc,
                                                float* __restrict__ ce,
                                                u64* __restrict__ clist,
                                                u32* __restrict__ ctrl) {
    int tid = threadIdx.x;
    int q = tid & 7;                          // sub-thread within box
    int gid = blockIdx.x * 32 + (tid >> 3);   // box id
    int b = gid >> 11;

    // gt-IoU argmax (g = q, q+8), first-occurrence tiebreak
    float4 bx = ((const float4*)boxes)[gid];
    float best = -1.0f;
    int bg = 0x7FFFFFFF;
    for (int g = q; g < GG; g += 8) {
        float4 gb = ((const float4*)gtb)[b * GG + g];
        float v = iou4(bx, gb);
        if (v > best) { best = v; bg = g; }   // ascending g: strict > = earliest
    }
    for (int d = 1; d < 8; d <<= 1) {
        float vo = __shfl_xor(best, d);
        int go = __shfl_xor(bg, d);
        if (vo > best || (vo == best && go < bg)) { best = vo; bg = go; }
    }
    int assigned = (best >= 0.5f) ? gtc[b * GG + bg] : 80;

    // online softmax over classes q, q+8, ... then 8-lane combine
    const float* lg = logits + (size_t)gid * CCH;
    float m = -INFINITY, s = 0.0f, m80 = -INFINITY, la = 0.0f;
    int arg = 0x7FFFFFFF;
    for (int c = q; c < CCH; c += 8) {
        float v = lg[c];
        if (v > m) { s *= expf(m - v); m = v; }
        s += expf(v - m);
        if (c < NCLS && v > m80) { m80 = v; arg = c; }
        if (c == assigned) la = v;
    }
    for (int d = 1; d < 8; d <<= 1) {
        float mo = __shfl_xor(m, d), so = __shfl_xor(s, d);
        float m80o = __shfl_xor(m80, d);
        int argo = __shfl_xor(arg, d);
        la += __shfl_xor(la, d);              // unique lane has nonzero
        float mn = fmaxf(m, mo);
        s = s * expf(m - mn) + so * expf(mo - mn);
        m = mn;
        if (m80o > m80 || (m80o == m80 && argo < arg)) { m80 = m80o; arg = argo; }
    }
    if (q == 0) {
        float sc = expf(m80 - m) / s;
        ce[gid] = (m + logf(s)) - la;
        if (sc >= 0.05f) {
            u32 slot = atomicAdd(&ctrl[b * NCLS + arg], 1u);
            if (slot < CAP) {
                u32 u = __float_as_uint(sc) | 0x80000000u;  // sc > 0
                clist[(size_t)(b * NCLS + arg) * CAP + slot] =
                    ((u64)u << 32) | (u64)(0xFFFFFFFFu - (u32)(gid & (NN - 1)));
            }
        }
    }
}

// Kernel 2: per-(image,class) NMS over its own compact list. One wave/block.
// Kept boxes append (key, ce) into the per-image human/object lists.
__global__ void __launch_bounds__(64) k_nms(const float* __restrict__ boxes,
                                            const float* __restrict__ ce,
                                            const u64* __restrict__ clist,
                                            u32* __restrict__ ctrl,
                                            u64* __restrict__ gkey,   // [2][BB][NN]
                                            float* __restrict__ gce) {
    __shared__ u64 key[CAP];
    __shared__ float4 bxs[CAP];
    __shared__ unsigned char sup[CAP];
    int b = blockIdx.x / NCLS;
    int c = blockIdx.x % NCLS;
    int lane = threadIdx.x;

    int k = (int)ctrl[b * NCLS + c];
    if (k > CAP) k = CAP;
    if (k == 0) return;

    for (int j = lane; j < k; j += 64)
        key[j] = clist[(size_t)(b * NCLS + c) * CAP + j];

    // bitonic sort descending (pad with 0 sorts last)
    int n2 = 1;
    while (n2 < k) n2 <<= 1;
    for (int j = k + lane; j < n2; j += 64) key[j] = 0;
    __syncthreads();
    for (int kk = 2; kk <= n2; kk <<= 1) {
        for (int j = kk >> 1; j > 0; j >>= 1) {
            for (int t = lane; t < n2; t += 64) {
                int ixj = t ^ j;
                if (ixj > t) {
                    u64 a = key[t], d = key[ixj];
                    bool sw = ((t & kk) == 0) ? (a < d) : (a > d);
                    if (sw) { key[t] = d; key[ixj] = a; }
                }
            }
            __syncthreads();
        }
    }

    for (int j = lane; j < k; j += 64) {
        u32 idx = 0xFFFFFFFFu - (u32)(key[j] & 0xFFFFFFFFull);
        bxs[j] = ((const float4*)boxes)[b * NN + idx];
        sup[j] = 0;
    }
    __syncthreads();

    for (int i = 0; i < k - 1; ++i) {
        if (!sup[i]) {
            float4 A = bxs[i];
            for (int j = i + 1 + lane; j < k; j += 64)
                if (!sup[j] && iou4(A, bxs[j]) > 0.5f) sup[j] = 1;
        }
        __syncthreads();
    }

    // append kept to per-image group list (0 = human class, 1 = object)
    int grp = (c == 0) ? 0 : 1;
    u32* cnt = &ctrl[1280 + grp * 16 + b];
    u64* dk = gkey + ((size_t)grp * BB + b) * NN;
    float* dc = gce + ((size_t)grp * BB + b) * NN;
    for (int chunk = 0; chunk < k; chunk += 64) {
        int j = chunk + lane;
        bool kp = (j < k) && !sup[j];
        u64 mask = __ballot(kp);
        u32 base = 0;
        if (lane == 0 && mask) base = atomicAdd(cnt, (u32)__popcll(mask));
        base = __shfl(base, 0);
        if (kp) {
            u32 slot = base + (u32)__popcll(mask & ((1ull << lane) - 1ull));
            u32 idx = 0xFFFFFFFFu - (u32)(key[j] & 0xFFFFFFFFull);
            dk[slot] = key[j];
            dc[slot] = ce[b * NN + idx];
        }
    }
}

// Kernel 3: per-image top-10 per group by key (desc) + CE sum; last block
// finishing does the final reduction (device-scope done counter).
__global__ void __launch_bounds__(256) k_select(const u64* __restrict__ gkey,
                                                const float* __restrict__ gce,
                                                u32* __restrict__ ctrl,
                                                float* __restrict__ partial,
                                                float* __restrict__ out) {
    __shared__ u64 skey[NN];
    __shared__ float sce[NN];
    __shared__ u64 wmax[4];
    __shared__ int wslot[4];
    int b = blockIdx.x;
    int tid = threadIdx.x;
    int lane = tid & 63, wid = tid >> 6;

    float ces = 0.0f;
    int total = 0;
    for (int grp = 0; grp < 2; ++grp) {
        int n = (int)ctrl[1280 + grp * 16 + b];   // <= NN by construction
        int m = n < 10 ? n : 10;
        total += m;
        if (m == 0) continue;
        const u64* sk = gkey + ((size_t)grp * BB + b) * NN;
        const float* sc = gce + ((size_t)grp * BB + b) * NN;
        for (int j = tid; j < n; j += 256) { skey[j] = sk[j]; sce[j] = sc[j]; }
        __syncthreads();

        u64 ck = 0; int cs = -1;
        for (int s = tid; s < n; s += 256) {
            u64 v = skey[s];
            if (v > ck) { ck = v; cs = s; }
        }
        for (int t = 0; t < m; ++t) {
            u64 k2 = ck; int s2 = cs;
            for (int d = 1; d < 64; d <<= 1) {
                u64 ok = __shfl_xor(k2, d);
                int os = __shfl_xor(s2, d);
                if (ok > k2) { k2 = ok; s2 = os; }
            }
            if (lane == 0) { wmax[wid] = k2; wslot[wid] = s2; }
            __syncthreads();
            u64 bk = wmax[0]; int bs = wslot[0];
            for (int w = 1; w < 4; ++w)
                if (wmax[w] > bk) { bk = wmax[w]; bs = wslot[w]; }
            ces += sce[bs];               // uniform; deterministic (keys unique)
            if (cs == bs) {               // unique owner rescans its slots
                skey[bs] = 0;
                ck = 0; cs = -1;
                for (int s = tid; s < n; s += 256) {
                    u64 v = skey[s];
                    if (v > ck) { ck = v; cs = s; }
                }
            }
            __syncthreads();
        }
        __syncthreads();                  // before LDS reuse by next group
    }
    if (tid == 0) {
        ((volatile float*)partial)[b * 2 + 0] = ces;
        ((volatile float*)partial)[b * 2 + 1] = (float)total;
        __threadfence();
        u32 t = atomicAdd(&ctrl[1312], 1u);
        if (t == BB - 1) {                // last image block: final reduce
            __threadfence();
            float cs2 = 0.0f, cn = 0.0f;
            for (int i = 0; i < BB; ++i) {
                cs2 += ((volatile float*)partial)[i * 2 + 0];
                cn += ((volatile float*)partial)[i * 2 + 1];
            }
            out[0] = cs2 / fmaxf(cn, 1.0f);
        }
    }
}

extern "C" void kernel_launch(void* const* d_in, const int* in_sizes, int n_in,
                              void* d_out, int out_size, void* d_ws, size_t ws_size,
                              hipStream_t stream) {
    const float* boxes = (const float*)d_in[0];       // (16,2048,4)
    const float* logits = (const float*)d_in[1];      // (16,2048,81)
    const float* gt_boxes = (const float*)d_in[2];    // (16,16,4)
    const int* gt_classes = (const int*)d_in[3];      // (16,16)
    float* out = (float*)d_out;

    char* ws = (char*)d_ws;
    size_t off = 0;
    auto alloc = [&](size_t bytes) {
        char* p = ws + off;
        off = (off + bytes + 255) & ~(size_t)255;
        return p;
    };
    u32* ctrl = (u32*)alloc(CTRL_WORDS * sizeof(u32));
    float* ce = (float*)alloc(BB * NN * sizeof(float));
    u64* clist = (u64*)alloc((size_t)BB * NCLS * CAP * sizeof(u64));
    u64* gkey = (u64*)alloc((size_t)2 * BB * NN * sizeof(u64));
    float* gce = (float*)alloc((size_t)2 * BB * NN * sizeof(float));
    float* partial = (float*)alloc(BB * 2 * sizeof(float));

    hipMemsetAsync(ctrl, 0, CTRL_WORDS * sizeof(u32), stream);
    k_perbox<<<BB * NN / 32, 256, 0, stream>>>(boxes, logits, gt_boxes, gt_classes,
                                               ce, clist, ctrl);
    k_nms<<<BB * NCLS, 64, 0, stream>>>(boxes, ce, clist, ctrl, gkey, gce);
    k_select<<<BB, 256, 0, stream>>>(gkey, gce, ctrl, partial, out);
}

// Round 5
// 72.622 us; speedup vs baseline: 1.0247x; 1.0247x over previous
//
#include <hip/hip_runtime.h>
#include <math.h>

#define BB 16
#define NN 2048
#define CCH 81
#define GG 16
#define NCLS 80
#define CAP 256   // per-(image,class) candidate cap; mean ~26, 256 = >40 sigma

typedef unsigned long long u64;
typedef unsigned int u32;

__device__ __forceinline__ float iou4(float4 a, float4 b) {
    float areaA = (a.z - a.x) * (a.w - a.y);
    float areaB = (b.z - b.x) * (b.w - b.y);
    float ltx = fmaxf(a.x, b.x), lty = fmaxf(a.y, b.y);
    float rbx = fminf(a.z, b.z), rby = fminf(a.w, b.w);
    float w = fmaxf(rbx - ltx, 0.0f), h = fmaxf(rby - lty, 0.0f);
    float inter = w * h;
    return inter / (areaA + areaB - inter + 1e-9f);
}

// ctrl layout (u32): [0,1280) ccnt  [1280,1296) hcnt  [1296,1312) ocnt  [1312] done
#define CTRL_WORDS 1313

// Kernel 0: zero the control block (kernel node, NOT a graph memset node —
// memset nodes go to the blit path and cost a cross-engine sync bubble).
__global__ void __launch_bounds__(256) k_zero(u32* __restrict__ ctrl) {
    for (int i = threadIdx.x; i < CTRL_WORDS; i += 256) ctrl[i] = 0;
}

// Kernel 1: 8 threads/box. Online softmax + argmax + gt-IoU + CE; active boxes
// append their priority key (score | ~idx) to the per-(image,class) list.
__global__ void __launch_bounds__(256) k_perbox(const float* __restrict__ boxes,
                                                const float* __restrict__ logits,
                                                const float* __restrict__ gtb,
                                                const int* __restrict__ gtc,
                                                float* __restrict__ ce,
                                                u64* __restrict__ clist,
                                                u32* __restrict__ ctrl) {
    int tid = threadIdx.x;
    int q = tid & 7;                          // sub-thread within box
    int gid = blockIdx.x * 32 + (tid >> 3);   // box id
    int b = gid >> 11;

    // gt-IoU argmax (g = q, q+8), first-occurrence tiebreak
    float4 bx = ((const float4*)boxes)[gid];
    float best = -1.0f;
    int bg = 0x7FFFFFFF;
    for (int g = q; g < GG; g += 8) {
        float4 gb = ((const float4*)gtb)[b * GG + g];
        float v = iou4(bx, gb);
        if (v > best) { best = v; bg = g; }   // ascending g: strict > = earliest
    }
    for (int d = 1; d < 8; d <<= 1) {
        float vo = __shfl_xor(best, d);
        int go = __shfl_xor(bg, d);
        if (vo > best || (vo == best && go < bg)) { best = vo; bg = go; }
    }
    int assigned = (best >= 0.5f) ? gtc[b * GG + bg] : 80;

    // online softmax over classes q, q+8, ... then 8-lane combine
    const float* lg = logits + (size_t)gid * CCH;
    float m = -INFINITY, s = 0.0f, m80 = -INFINITY, la = 0.0f;
    int arg = 0x7FFFFFFF;
    for (int c = q; c < CCH; c += 8) {
        float v = lg[c];
        if (v > m) { s *= expf(m - v); m = v; }
        s += expf(v - m);
        if (c < NCLS && v > m80) { m80 = v; arg = c; }
        if (c == assigned) la = v;
    }
    for (int d = 1; d < 8; d <<= 1) {
        float mo = __shfl_xor(m, d), so = __shfl_xor(s, d);
        float m80o = __shfl_xor(m80, d);
        int argo = __shfl_xor(arg, d);
        la += __shfl_xor(la, d);              // unique lane has nonzero
        float mn = fmaxf(m, mo);
        s = s * expf(m - mn) + so * expf(mo - mn);
        m = mn;
        if (m80o > m80 || (m80o == m80 && argo < arg)) { m80 = m80o; arg = argo; }
    }
    if (q == 0) {
        float sc = expf(m80 - m) / s;
        ce[gid] = (m + logf(s)) - la;
        if (sc >= 0.05f) {
            u32 slot = atomicAdd(&ctrl[b * NCLS + arg], 1u);
            if (slot < CAP) {
                u32 u = __float_as_uint(sc) | 0x80000000u;  // sc > 0
                clist[(size_t)(b * NCLS + arg) * CAP + slot] =
                    ((u64)u << 32) | (u64)(0xFFFFFFFFu - (u32)(gid & (NN - 1)));
            }
        }
    }
}

// Kernel 2: per-(image,class) NMS over its own compact list. One wave/block.
// Kept boxes append (key, ce) into the per-image human/object lists.
__global__ void __launch_bounds__(64) k_nms(const float* __restrict__ boxes,
                                            const float* __restrict__ ce,
                                            const u64* __restrict__ clist,
                                            u32* __restrict__ ctrl,
                                            u64* __restrict__ gkey,   // [2][BB][NN]
                                            float* __restrict__ gce) {
    __shared__ u64 key[CAP];
    __shared__ float4 bxs[CAP];
    __shared__ unsigned char sup[CAP];
    int b = blockIdx.x / NCLS;
    int c = blockIdx.x % NCLS;
    int lane = threadIdx.x;

    int k = (int)ctrl[b * NCLS + c];
    if (k > CAP) k = CAP;
    if (k == 0) return;

    for (int j = lane; j < k; j += 64)
        key[j] = clist[(size_t)(b * NCLS + c) * CAP + j];

    // bitonic sort descending (pad with 0 sorts last)
    int n2 = 1;
    while (n2 < k) n2 <<= 1;
    for (int j = k + lane; j < n2; j += 64) key[j] = 0;
    __syncthreads();
    for (int kk = 2; kk <= n2; kk <<= 1) {
        for (int j = kk >> 1; j > 0; j >>= 1) {
            for (int t = lane; t < n2; t += 64) {
                int ixj = t ^ j;
                if (ixj > t) {
                    u64 a = key[t], d = key[ixj];
                    bool sw = ((t & kk) == 0) ? (a < d) : (a > d);
                    if (sw) { key[t] = d; key[ixj] = a; }
                }
            }
            __syncthreads();
        }
    }

    for (int j = lane; j < k; j += 64) {
        u32 idx = 0xFFFFFFFFu - (u32)(key[j] & 0xFFFFFFFFull);
        bxs[j] = ((const float4*)boxes)[b * NN + idx];
        sup[j] = 0;
    }
    __syncthreads();

    for (int i = 0; i < k - 1; ++i) {
        if (!sup[i]) {
            float4 A = bxs[i];
            for (int j = i + 1 + lane; j < k; j += 64)
                if (!sup[j] && iou4(A, bxs[j]) > 0.5f) sup[j] = 1;
        }
        __syncthreads();
    }

    // append kept to per-image group list (0 = human class, 1 = object)
    int grp = (c == 0) ? 0 : 1;
    u32* cnt = &ctrl[1280 + grp * 16 + b];
    u64* dk = gkey + ((size_t)grp * BB + b) * NN;
    float* dc = gce + ((size_t)grp * BB + b) * NN;
    for (int chunk = 0; chunk < k; chunk += 64) {
        int j = chunk + lane;
        bool kp = (j < k) && !sup[j];
        u64 mask = __ballot(kp);
        u32 base = 0;
        if (lane == 0 && mask) base = atomicAdd(cnt, (u32)__popcll(mask));
        base = __shfl(base, 0);
        if (kp) {
            u32 slot = base + (u32)__popcll(mask & ((1ull << lane) - 1ull));
            u32 idx = 0xFFFFFFFFu - (u32)(key[j] & 0xFFFFFFFFull);
            dk[slot] = key[j];
            dc[slot] = ce[b * NN + idx];
        }
    }
}

// Kernel 3: per-image top-10 per group by key (desc) + CE sum; last block
// finishing does the final reduction (device-scope done counter).
__global__ void __launch_bounds__(256) k_select(const u64* __restrict__ gkey,
                                                const float* __restrict__ gce,
                                                u32* __restrict__ ctrl,
                                                float* __restrict__ partial,
                                                float* __restrict__ out) {
    __shared__ u64 skey[NN];
    __shared__ float sce[NN];
    __shared__ u64 wmax[4];
    __shared__ int wslot[4];
    int b = blockIdx.x;
    int tid = threadIdx.x;
    int lane = tid & 63, wid = tid >> 6;

    float ces = 0.0f;
    int total = 0;
    for (int grp = 0; grp < 2; ++grp) {
        int n = (int)ctrl[1280 + grp * 16 + b];   // <= NN by construction
        int m = n < 10 ? n : 10;
        total += m;
        if (m == 0) continue;
        const u64* sk = gkey + ((size_t)grp * BB + b) * NN;
        const float* sc = gce + ((size_t)grp * BB + b) * NN;
        for (int j = tid; j < n; j += 256) { skey[j] = sk[j]; sce[j] = sc[j]; }
        __syncthreads();

        u64 ck = 0; int cs = -1;
        for (int s = tid; s < n; s += 256) {
            u64 v = skey[s];
            if (v > ck) { ck = v; cs = s; }
        }
        for (int t = 0; t < m; ++t) {
            u64 k2 = ck; int s2 = cs;
            for (int d = 1; d < 64; d <<= 1) {
                u64 ok = __shfl_xor(k2, d);
                int os = __shfl_xor(s2, d);
                if (ok > k2) { k2 = ok; s2 = os; }
            }
            if (lane == 0) { wmax[wid] = k2; wslot[wid] = s2; }
            __syncthreads();
            u64 bk = wmax[0]; int bs = wslot[0];
            for (int w = 1; w < 4; ++w)
                if (wmax[w] > bk) { bk = wmax[w]; bs = wslot[w]; }
            ces += sce[bs];               // uniform; deterministic (keys unique)
            if (cs == bs) {               // unique owner rescans its slots
                skey[bs] = 0;
                ck = 0; cs = -1;
                for (int s = tid; s < n; s += 256) {
                    u64 v = skey[s];
                    if (v > ck) { ck = v; cs = s; }
                }
            }
            __syncthreads();
        }
        __syncthreads();                  // before LDS reuse by next group
    }
    if (tid == 0) {
        ((volatile float*)partial)[b * 2 + 0] = ces;
        ((volatile float*)partial)[b * 2 + 1] = (float)total;
        __threadfence();
        u32 t = atomicAdd(&ctrl[1312], 1u);
        if (t == BB - 1) {                // last image block: final reduce
            __threadfence();
            float cs2 = 0.0f, cn = 0.0f;
            for (int i = 0; i < BB; ++i) {
                cs2 += ((volatile float*)partial)[i * 2 + 0];
                cn += ((volatile float*)partial)[i * 2 + 1];
            }
            out[0] = cs2 / fmaxf(cn, 1.0f);
        }
    }
}

extern "C" void kernel_launch(void* const* d_in, const int* in_sizes, int n_in,
                              void* d_out, int out_size, void* d_ws, size_t ws_size,
                              hipStream_t stream) {
    const float* boxes = (const float*)d_in[0];       // (16,2048,4)
    const float* logits = (const float*)d_in[1];      // (16,2048,81)
    const float* gt_boxes = (const float*)d_in[2];    // (16,16,4)
    const int* gt_classes = (const int*)d_in[3];      // (16,16)
    float* out = (float*)d_out;

    char* ws = (char*)d_ws;
    size_t off = 0;
    auto alloc = [&](size_t bytes) {
        char* p = ws + off;
        off = (off + bytes + 255) & ~(size_t)255;
        return p;
    };
    u32* ctrl = (u32*)alloc(CTRL_WORDS * sizeof(u32));
    float* ce = (float*)alloc(BB * NN * sizeof(float));
    u64* clist = (u64*)alloc((size_t)BB * NCLS * CAP * sizeof(u64));
    u64* gkey = (u64*)alloc((size_t)2 * BB * NN * sizeof(u64));
    float* gce = (float*)alloc((size_t)2 * BB * NN * sizeof(float));
    float* partial = (float*)alloc(BB * 2 * sizeof(float));

    k_zero<<<1, 256, 0, stream>>>(ctrl);
    k_perbox<<<BB * NN / 32, 256, 0, stream>>>(boxes, logits, gt_boxes, gt_classes,
                                               ce, clist, ctrl);
    k_nms<<<BB * NCLS, 64, 0, stream>>>(boxes, ce, clist, ctrl, gkey, gce);
    k_select<<<BB, 256, 0, stream>>>(gkey, gce, ctrl, partial, out);
}

// Round 6
// 65.082 us; speedup vs baseline: 1.1435x; 1.1159x over previous
//
#include <hip/hip_runtime.h>
#include <math.h>

#define BB 16
#define NN 2048
#define CCH 81
#define GG 16
#define NCLS 80
#define CAP 512   // per-(image,class) candidate cap; mean ~26, P(>512)~0

typedef unsigned long long u64;
typedef unsigned int u32;
typedef float f4_t __attribute__((ext_vector_type(4)));
typedef f4_t uf4 __attribute__((aligned(4)));   // logit rows are only 4B-aligned

__device__ __forceinline__ float iou4(float4 a, float4 b) {
    float areaA = (a.z - a.x) * (a.w - a.y);
    float areaB = (b.z - b.x) * (b.w - b.y);
    float ltx = fmaxf(a.x, b.x), lty = fmaxf(a.y, b.y);
    float rbx = fminf(a.z, b.z), rby = fminf(a.w, b.w);
    float w = fmaxf(rbx - ltx, 0.0f), h = fmaxf(rby - lty, 0.0f);
    float inter = w * h;
    return inter / (areaA + areaB - inter + 1e-9f);
}

// Kernel 1: 8 threads/box, float4 logit loads. Two-pass register softmax,
// argmax (first-occurrence), gt-IoU argmax, CE. Zeroes keep and done.
__global__ void __launch_bounds__(256) k_perbox(const float* __restrict__ boxes,
                                                const float* __restrict__ logits,
                                                const float* __restrict__ gtb,
                                                const int* __restrict__ gtc,
                                                float* __restrict__ score,
                                                float* __restrict__ ce,
                                                unsigned char* __restrict__ label,
                                                unsigned char* __restrict__ keep,
                                                u32* __restrict__ done) {
    int tid = threadIdx.x;
    int q = tid & 7;                          // sub-thread within box
    int gid = blockIdx.x * 32 + (tid >> 3);   // box id
    int b = gid >> 11;
    if (blockIdx.x == 0 && tid == 0) *done = 0;   // upstream node zeroes ctrl
    if (tid < 32) keep[blockIdx.x * 32 + tid] = 0;

    // gt-IoU argmax (g = q, q+8), first-occurrence tiebreak
    float4 bx = ((const float4*)boxes)[gid];
    float best = -1.0f;
    int bg = 0x7FFFFFFF;
    for (int g = q; g < GG; g += 8) {
        float4 gb = ((const float4*)gtb)[b * GG + g];
        float v = iou4(bx, gb);
        if (v > best) { best = v; bg = g; }   // ascending g: strict > = earliest
    }
    for (int d = 1; d < 8; d <<= 1) {
        float vo = __shfl_xor(best, d);
        int go = __shfl_xor(bg, d);
        if (vo > best || (vo == best && go < bg)) { best = vo; bg = go; }
    }
    int assigned = (best >= 0.5f) ? gtc[b * GG + bg] : 80;

    // vectorized logit loads: lane q owns classes {4q..4q+3, 32+4q..32+4q+3,
    // [64+4q..64+4q+3 if q<4]}; lane 7 also owns class 80.
    const float* lg = logits + (size_t)gid * CCH;
    uf4 v0 = *(const uf4*)(lg + 4 * q);
    uf4 v1 = *(const uf4*)(lg + 32 + 4 * q);
    bool has2 = (q < 4);
    uf4 v2 = v0;
    if (has2) v2 = *(const uf4*)(lg + 64 + 4 * q);
    float v80 = (q == 7) ? lg[80] : -INFINITY;

    // local max over all owned classes; argmax over owned classes < 80
    // (visit in ascending c per lane; strict > = first occurrence)
    float m = v80, m80 = -INFINITY, la = 0.0f;
    int arg = 0x7FFFFFFF;
    #pragma unroll
    for (int k = 0; k < 4; ++k) {
        float a0 = v0[k];
        int c0 = 4 * q + k;
        m = fmaxf(m, a0);
        if (a0 > m80) { m80 = a0; arg = c0; }
        if (c0 == assigned) la = a0;
    }
    #pragma unroll
    for (int k = 0; k < 4; ++k) {
        float a1 = v1[k];
        int c1 = 32 + 4 * q + k;
        m = fmaxf(m, a1);
        if (a1 > m80) { m80 = a1; arg = c1; }
        if (c1 == assigned) la = a1;
    }
    if (has2) {
        #pragma unroll
        for (int k = 0; k < 4; ++k) {
            float a2 = v2[k];
            int c2 = 64 + 4 * q + k;
            m = fmaxf(m, a2);
            if (a2 > m80) { m80 = a2; arg = c2; }
            if (c2 == assigned) la = a2;
        }
    }
    if (q == 7 && assigned == 80) la = v80;

    // combine max across the 8-lane group
    for (int d = 1; d < 8; d <<= 1) m = fmaxf(m, __shfl_xor(m, d));

    // exp-sum with the global max (values already in registers)
    float s = (q == 7) ? expf(v80 - m) : 0.0f;
    #pragma unroll
    for (int k = 0; k < 4; ++k) s += expf(v0[k] - m) + expf(v1[k] - m);
    if (has2) {
        #pragma unroll
        for (int k = 0; k < 4; ++k) s += expf(v2[k] - m);
    }

    // combine s, (m80,arg), la across the 8-lane group
    for (int d = 1; d < 8; d <<= 1) {
        s += __shfl_xor(s, d);
        float m80o = __shfl_xor(m80, d);
        int argo = __shfl_xor(arg, d);
        if (m80o > m80 || (m80o == m80 && argo < arg)) { m80 = m80o; arg = argo; }
        la += __shfl_xor(la, d);              // unique owner lane has nonzero
    }

    if (q == 0) {
        float sc = expf(m80 - m) / s;
        ce[gid] = (m + logf(s)) - la;
        score[gid] = sc;
        label[gid] = (sc >= 0.05f) ? (unsigned char)arg : (unsigned char)0xFF;
    }
}

// Kernel 2: per-(image,class) NMS. One wave/block; coalesced label scan builds
// the candidate list (cross-class IoU is exactly 0 via the class-offset trick).
__global__ void __launch_bounds__(64) k_nms(const float* __restrict__ boxes,
                                            const float* __restrict__ score,
                                            const unsigned char* __restrict__ label,
                                            unsigned char* __restrict__ keep) {
    __shared__ u64 key[CAP];
    __shared__ float4 bxs[CAP];
    __shared__ unsigned char sup[CAP];
    int b = blockIdx.x / NCLS;
    int c = blockIdx.x % NCLS;
    int lane = threadIdx.x;

    int k = 0;
    for (int chunk = 0; chunk < NN; chunk += 64) {
        int i = chunk + lane;
        bool match = (label[b * NN + i] == (unsigned char)c);
        u64 mask = __ballot(match);
        if (match) {
            int slot = k + __popcll(mask & ((1ull << lane) - 1ull));
            if (slot < CAP) {
                u32 u = __float_as_uint(score[b * NN + i]) | 0x80000000u;
                key[slot] = ((u64)u << 32) | (u64)(0xFFFFFFFFu - (u32)i);
            }
        }
        k += __popcll(mask);
    }
    if (k > CAP) k = CAP;
    if (k == 0) return;

    int n2 = 1;
    while (n2 < k) n2 <<= 1;
    for (int j = k + lane; j < n2; j += 64) key[j] = 0;
    __syncthreads();
    for (int kk = 2; kk <= n2; kk <<= 1) {
        for (int j = kk >> 1; j > 0; j >>= 1) {
            for (int t = lane; t < n2; t += 64) {
                int ixj = t ^ j;
                if (ixj > t) {
                    u64 a = key[t], d = key[ixj];
                    bool sw = ((t & kk) == 0) ? (a < d) : (a > d);
                    if (sw) { key[t] = d; key[ixj] = a; }
                }
            }
            __syncthreads();
        }
    }

    for (int j = lane; j < k; j += 64) {
        u32 idx = 0xFFFFFFFFu - (u32)(key[j] & 0xFFFFFFFFull);
        bxs[j] = ((const float4*)boxes)[b * NN + idx];
        sup[j] = 0;
    }
    __syncthreads();

    for (int i = 0; i < k - 1; ++i) {
        if (!sup[i]) {
            float4 A = bxs[i];
            for (int j = i + 1 + lane; j < k; j += 64)
                if (!sup[j] && iou4(A, bxs[j]) > 0.5f) sup[j] = 1;
        }
        __syncthreads();
    }

    for (int j = lane; j < k; j += 64) {
        if (!sup[j]) {
            u32 idx = 0xFFFFFFFFu - (u32)(key[j] & 0xFFFFFFFFull);
            keep[b * NN + idx] = 1;   // classes partition boxes: no races
        }
    }
}

// Kernel 3: per-image top-10 per group among kept, by (score desc, idx asc):
// LDS compaction + tournament extraction; last block does the final reduce.
__global__ void __launch_bounds__(256) k_select(const unsigned char* __restrict__ keep,
                                                const unsigned char* __restrict__ label,
                                                const float* __restrict__ score,
                                                const float* __restrict__ ce,
                                                float* __restrict__ partial,
                                                u32* __restrict__ done,
                                                float* __restrict__ out) {
    __shared__ u64 skey[NN];
    __shared__ float sce[NN];
    __shared__ int cnts[2];
    __shared__ u64 wmax[4];
    __shared__ int wslot[4];
    int b = blockIdx.x;
    int tid = threadIdx.x;
    int lane = tid & 63, wid = tid >> 6;
    if (tid < 2) cnts[tid] = 0;
    __syncthreads();

    for (int chunk = 0; chunk < NN; chunk += 256) {
        int i = chunk + tid;
        bool kp = keep[b * NN + i] != 0;
        unsigned char lb = label[b * NN + i];
        bool h = kp && (lb == 0);
        bool o = kp && (lb != 0) && (lb != 0xFF);
        u64 hm = __ballot(h), om = __ballot(o);
        int hbase = 0, obase = 0;
        if (lane == 0) {
            if (hm) hbase = atomicAdd(&cnts[0], __popcll(hm));
            if (om) obase = atomicAdd(&cnts[1], __popcll(om));
        }
        hbase = __shfl(hbase, 0);
        obase = __shfl(obase, 0);
        if (h | o) {
            u64 below = (1ull << lane) - 1ull;
            u32 u = __float_as_uint(score[b * NN + i]) | 0x80000000u;
            u64 kv = ((u64)u << 32) | (u64)(0xFFFFFFFFu - (u32)i);
            int slot = h ? (hbase + __popcll(hm & below))
                         : (NN - 1 - (obase + __popcll(om & below)));
            skey[slot] = kv;
            sce[slot] = ce[b * NN + i];
        }
    }
    __syncthreads();
    int hc = cnts[0], oc = cnts[1];

    float ces = 0.0f;
    for (int grp = 0; grp < 2; ++grp) {
        int n = grp ? oc : hc;
        int start = grp ? (NN - oc) : 0;
        int m = n < 10 ? n : 10;
        if (m == 0) continue;
        if (n <= 10) {                        // order-free: plain sum
            float lsum = 0.0f;
            for (int j = lane; j < n; j += 64) lsum += sce[start + j];
            for (int d = 32; d; d >>= 1) lsum += __shfl_xor(lsum, d);
            ces += lsum;
            continue;
        }
        u64 ck = 0; int cs = -1;
        for (int s = start + tid; s < start + n; s += 256) {
            u64 v = skey[s];
            if (v > ck) { ck = v; cs = s; }
        }
        for (int t = 0; t < m; ++t) {
            u64 k2 = ck; int s2 = cs;
            for (int d = 1; d < 64; d <<= 1) {
                u64 ok = __shfl_xor(k2, d);
                int os = __shfl_xor(s2, d);
                if (ok > k2) { k2 = ok; s2 = os; }
            }
            if (lane == 0) { wmax[wid] = k2; wslot[wid] = s2; }
            __syncthreads();
            u64 bk = wmax[0]; int bs = wslot[0];
            for (int w = 1; w < 4; ++w)
                if (wmax[w] > bk) { bk = wmax[w]; bs = wslot[w]; }
            ces += sce[bs];                   // uniform; keys unique
            if (cs == bs) {
                skey[bs] = 0;
                ck = 0; cs = -1;
                for (int s = start + tid; s < start + n; s += 256) {
                    u64 v = skey[s];
                    if (v > ck) { ck = v; cs = s; }
                }
            }
            __syncthreads();
        }
        __syncthreads();
    }
    if (tid == 0) {
        ((volatile float*)partial)[b * 2 + 0] = ces;
        ((volatile float*)partial)[b * 2 + 1] = (float)((hc < 10 ? hc : 10) +
                                                        (oc < 10 ? oc : 10));
        __threadfence();
        u32 t = atomicAdd(done, 1u);
        if (t == BB - 1) {
            __threadfence();
            float cs2 = 0.0f, cn = 0.0f;
            for (int i = 0; i < BB; ++i) {
                cs2 += ((volatile float*)partial)[i * 2 + 0];
                cn += ((volatile float*)partial)[i * 2 + 1];
            }
            out[0] = cs2 / fmaxf(cn, 1.0f);
        }
    }
}

extern "C" void kernel_launch(void* const* d_in, const int* in_sizes, int n_in,
                              void* d_out, int out_size, void* d_ws, size_t ws_size,
                              hipStream_t stream) {
    const float* boxes = (const float*)d_in[0];       // (16,2048,4)
    const float* logits = (const float*)d_in[1];      // (16,2048,81)
    const float* gt_boxes = (const float*)d_in[2];    // (16,16,4)
    const int* gt_classes = (const int*)d_in[3];      // (16,16)
    float* out = (float*)d_out;

    char* ws = (char*)d_ws;
    size_t off = 0;
    auto alloc = [&](size_t bytes) {
        char* p = ws + off;
        off = (off + bytes + 255) & ~(size_t)255;
        return p;
    };
    float* score = (float*)alloc(BB * NN * sizeof(float));
    float* ce = (float*)alloc(BB * NN * sizeof(float));
    unsigned char* label = (unsigned char*)alloc(BB * NN);
    unsigned char* keep = (unsigned char*)alloc(BB * NN);
    float* partial = (float*)alloc(BB * 2 * sizeof(float));
    u32* done = (u32*)alloc(sizeof(u32));

    k_perbox<<<BB * NN / 32, 256, 0, stream>>>(boxes, logits, gt_boxes, gt_classes,
                                               score, ce, label, keep, done);
    k_nms<<<BB * NCLS, 64, 0, stream>>>(boxes, score, label, keep);
    k_select<<<BB, 256, 0, stream>>>(keep, label, score, ce, partial, done, out);
}